// Round 8
// baseline (117.432 us; speedup 1.0000x reference)
//
#include <hip/hip_runtime.h>
#include <math.h>

#define EPSF 1e-8f

typedef float f2v __attribute__((ext_vector_type(2)));

__device__ __forceinline__ float bcf(int x){ return __builtin_bit_cast(float, x); }
__device__ __forceinline__ int   bci(float x){ return __builtin_bit_cast(int, x); }

template<int CTRL, int RM>
__device__ __forceinline__ float dpp0(float v){
  return bcf(__builtin_amdgcn_update_dpp(0, bci(v), CTRL, RM, 0xF, false));
}
__device__ __forceinline__ float rl(float v, int l){
  return bcf(__builtin_amdgcn_readlane(bci(v), l));
}
__device__ __forceinline__ float wave_iscan_add(float v){
  v += dpp0<0x111,0xF>(v);
  v += dpp0<0x112,0xF>(v);
  v += dpp0<0x114,0xF>(v);
  v += dpp0<0x118,0xF>(v);
  v += dpp0<0x142,0xA>(v);
  v += dpp0<0x143,0xC>(v);
  return v;
}
__device__ __forceinline__ float wave_red_add(float v){ return wave_iscan_add(v); } // lane63 = total
__device__ __forceinline__ float wave_red_max_pos(float v){ // v >= 0
  v = fmaxf(v, dpp0<0x111,0xF>(v));
  v = fmaxf(v, dpp0<0x112,0xF>(v));
  v = fmaxf(v, dpp0<0x114,0xF>(v));
  v = fmaxf(v, dpp0<0x118,0xF>(v));
  v = fmaxf(v, dpp0<0x142,0xA>(v));
  v = fmaxf(v, dpp0<0x143,0xC>(v));
  return v;
}

// 8B-unit swizzle on the 512-complex buffer: slot(b[3:0]) ^= b[7:4].
// Verified at conflict floor for all 6 patterns (T1 wA/wB, T1 rA/rB, T2 w, T2 r).
__device__ __forceinline__ int FL(int i){ return i ^ ((i >> 4) & 15); }

// stats LDS slots (per wave): 0 SUMSQ, 1 ALT, 2..11 R1..R10, 12 STR, 13 STR2,
// 14 SC, 15 SC2, 16 SUMX, 17..26 Slo, 27..36 Shi pool, 37 x0, 38 xl
__global__ void __launch_bounds__(128, 2)
sr_kernel(const float* __restrict__ x,
          const float* __restrict__ ln_w, const float* __restrict__ ln_b,
          const float* __restrict__ w1, const float* __restrict__ b1,
          const float* __restrict__ w2, const float* __restrict__ b2,
          float* __restrict__ out, int B)
{
  __shared__ __align__(16) float2 buf2[2][512];     // 4KB per wave
  __shared__ __align__(16) float stats2[2][40];

  const int tid = threadIdx.x;
  const int t   = tid & 63;
  const int wv  = tid >> 6;
  const int row = blockIdx.x * 2 + wv;
  if (row >= B) return;
  const float* __restrict__ xr = x + (size_t)row * 1024;
  float2* buf = buf2[wv];
  float*  st  = stats2[wv];

  // ---- loads: own 16 + 12 right + 12 left neighbors ----
  const int c0 = t * 16;
  float vv[28];
  {
    const float4 a0 = *reinterpret_cast<const float4*>(xr + c0);
    const float4 a1 = *reinterpret_cast<const float4*>(xr + c0 + 4);
    const float4 a2 = *reinterpret_cast<const float4*>(xr + c0 + 8);
    const float4 a3 = *reinterpret_cast<const float4*>(xr + c0 + 12);
    vv[0]=a0.x; vv[1]=a0.y; vv[2]=a0.z; vv[3]=a0.w;
    vv[4]=a1.x; vv[5]=a1.y; vv[6]=a1.z; vv[7]=a1.w;
    vv[8]=a2.x; vv[9]=a2.y; vv[10]=a2.z; vv[11]=a2.w;
    vv[12]=a3.x; vv[13]=a3.y; vv[14]=a3.z; vv[15]=a3.w;
    if (t < 63) {
      const float4 n0 = *reinterpret_cast<const float4*>(xr + c0 + 16);
      const float4 n1 = *reinterpret_cast<const float4*>(xr + c0 + 20);
      const float4 n2 = *reinterpret_cast<const float4*>(xr + c0 + 24);
      vv[16]=n0.x; vv[17]=n0.y; vv[18]=n0.z; vv[19]=n0.w;
      vv[20]=n1.x; vv[21]=n1.y; vv[22]=n1.z; vv[23]=n1.w;
      vv[24]=n2.x; vv[25]=n2.y; vv[26]=n2.z; vv[27]=n2.w;
    } else {
#pragma unroll
      for (int j = 16; j < 28; ++j) vv[j] = 0.f;
    }
  }
  float pv[12];
  if (t > 0) {
    const float4 p0 = *reinterpret_cast<const float4*>(xr + c0 - 12);
    const float4 p1 = *reinterpret_cast<const float4*>(xr + c0 - 8);
    const float4 p2 = *reinterpret_cast<const float4*>(xr + c0 - 4);
    pv[0]=p0.x; pv[1]=p0.y; pv[2]=p0.z; pv[3]=p0.w;
    pv[4]=p1.x; pv[5]=p1.y; pv[6]=p1.z; pv[7]=p1.w;
    pv[8]=p2.x; pv[9]=p2.y; pv[10]=p2.z; pv[11]=p2.w;
  } else {
#pragma unroll
    for (int j = 0; j < 12; ++j) pv[j] = 0.f;
  }

  // ---- per-thread stats (packed f32 math -> v_pk_fma) ----
  {
    f2v sq2 = {0.f, 0.f}, al2 = {0.f, 0.f};
#pragma unroll
    for (int j = 0; j < 16; j += 2) {
      f2v a = {vv[j], vv[j+1]};
      sq2 += a * a;
      al2 += a;
    }
    float r;
    r = wave_red_add(sq2.x + sq2.y); if (t == 63) st[0] = r;
    r = wave_red_add(al2.x - al2.y); if (t == 63) st[1] = r;
  }
#pragma unroll
  for (int k = 1; k <= 10; ++k) {
    f2v acc = {0.f, 0.f};
#pragma unroll
    for (int j = 0; j < 16; j += 2) {
      f2v a = {vv[j], vv[j+1]};
      f2v b = {vv[j+k], vv[j+k+1]};
      acc += a * b;
    }
    float r = wave_red_add(acc.x + acc.y);
    if (t == 63) st[1 + k] = r;
  }

  // ---- prefix sums ----
  float s[16];
  s[0] = vv[0];
#pragma unroll
  for (int j = 1; j < 16; ++j) s[j] = s[j-1] + vv[j];
  const float cs16 = s[15];
  const float incl = wave_iscan_add(cs16);
  const float excl = incl - cs16;
#pragma unroll
  for (int j = 0; j < 16; ++j) s[j] += excl;
  if (t == 63) st[16] = incl;                       // SUMX
  if (t == 0) {
#pragma unroll
    for (int q = 0; q < 10; ++q) st[17 + q] = s[q];
    st[37] = vv[0];
  }
  if (t == 63) {
#pragma unroll
    for (int q = 0; q < 10; ++q) st[27 + q] = s[5 + q];
    st[38] = vv[15];
  }

  // ---- trend via sliding +-12 window ----
  float trv[16];
  float str = 0.f, str2 = 0.f;
  {
    float wsum = 0.f;
#pragma unroll
    for (int j = 0; j < 12; ++j) wsum += pv[j];
#pragma unroll
    for (int j = 0; j <= 12; ++j) wsum += vv[j];
#pragma unroll
    for (int jj = 0; jj < 16; ++jj) {
      if (jj > 0) {
        const float addv = vv[jj + 12];
        const float subv = (jj < 13) ? pv[jj - 1] : vv[jj - 13];
        wsum += addv - subv;
      }
      float swc = wsum;
      if (t == 0  && jj < 12) swc += (float)(12 - jj) * vv[0];
      if (t == 63 && jj >= 4) swc += (float)(jj - 3) * vv[15];
      const float tv = swc * 0.04f;
      trv[jj] = tv;
      str += tv;
      str2 = fmaf(tv, tv, str2);
    }
  }
  const float tincl = wave_iscan_add(str);
  if (t == 63) st[12] = tincl;
  { float r = wave_red_add(str2); if (t == 63) st[13] = r; }
  {
    const float texcl = tincl - str;
    float run = texcl, sc = 0.f, sc2 = 0.f;
#pragma unroll
    for (int jj = 0; jj < 16; ++jj) {
      run += trv[jj];
      const float cv = s[jj] - run;
      sc += cv;
      sc2 = fmaf(cv, cv, sc2);
    }
    float r;
    r = wave_red_add(sc);  if (t == 63) st[14] = r;
    r = wave_red_add(sc2); if (t == 63) st[15] = r;
  }

  // ---- strided reload for FFT ownership ----
  float xs[4][4];
#pragma unroll
  for (int a = 0; a < 4; ++a)
#pragma unroll
    for (int b = 0; b < 4; ++b)
      xs[a][b] = xr[(a << 8) + (b << 6) + t];

  constexpr float C22 = 0.9238795325112867f, S22 = 0.3826834323650898f, C45 = 0.7071067811865476f;
  const float OB1r[4] = {1.f,  C22,  C45,  S22};
  const float OB1i[4] = {0.f, -S22, -C45, -C22};
  const float OB2r[4] = {1.f,  C45,  0.f, -C45};
  const float OB2i[4] = {0.f, -C45, -1.f, -C45};
  const float OB3r[4] = {1.f,  S22, -C45, -C22};
  const float OB3i[4] = {0.f, -C22, -C45,  S22};

  // ---- FFT stage 1 (LEN=1024, real inputs) ----
  const float ang1 = -0.0061359231515425649f * (float)t;
  const float c1t = __cosf(ang1), s1t = __sinf(ang1);
  const float c2t = c1t*c1t - s1t*s1t, s2t = 2.f*c1t*s1t;
  const float c3t = c1t*c2t - s1t*s2t, s3t = s1t*c2t + c1t*s2t;
  float fRr[4][4], fRi[4][4];
#pragma unroll
  for (int b = 0; b < 4; ++b) {
    const float tw1r = c1t*OB1r[b] - s1t*OB1i[b], tw1i = c1t*OB1i[b] + s1t*OB1r[b];
    const float tw2r = c2t*OB2r[b] - s2t*OB2i[b], tw2i = c2t*OB2i[b] + s2t*OB2r[b];
    const float tw3r = c3t*OB3r[b] - s3t*OB3i[b], tw3i = c3t*OB3i[b] + s3t*OB3r[b];
    const float X0 = xs[0][b], X1 = xs[1][b], X2 = xs[2][b], X3 = xs[3][b];
    const float t0 = X0 + X2, t1 = X0 - X2, t2 = X1 + X3, t3 = X1 - X3;
    fRr[0][b] = t0 + t2;                 fRi[0][b] = 0.f;
    fRr[1][b] = t1*tw1r + t3*tw1i;       fRi[1][b] = t1*tw1i - t3*tw1r;
    const float y2 = t0 - t2;
    fRr[2][b] = y2*tw2r;                 fRi[2][b] = y2*tw2i;
    fRr[3][b] = t1*tw3r - t3*tw3i;       fRi[3][b] = t1*tw3i + t3*tw3r;
  }

  // ---- FFT stage 2 (LEN=256) ----
  const float c4 = c2t*c2t - s2t*s2t,  s4 = 2.f*c2t*s2t;
  const float c8 = c4*c4 - s4*s4,      s8 = 2.f*c4*s4;
  const float c12 = c4*c8 - s4*s8,     s12 = s4*c8 + c4*s8;
#pragma unroll
  for (int a = 0; a < 4; ++a) {
    const float A0r=fRr[a][0], A0i=fRi[a][0], A1r=fRr[a][1], A1i=fRi[a][1];
    const float A2r=fRr[a][2], A2i=fRi[a][2], A3r=fRr[a][3], A3i=fRi[a][3];
    const float t0r=A0r+A2r, t0i=A0i+A2i, t1r=A0r-A2r, t1i=A0i-A2i;
    const float t2r=A1r+A3r, t2i=A1i+A3i, t3r=A1r-A3r, t3i=A1i-A3i;
    fRr[a][0] = t0r + t2r;  fRi[a][0] = t0i + t2i;
    const float y1r = t1r + t3i, y1i = t1i - t3r;
    fRr[a][1] = y1r*c4 - y1i*s4;    fRi[a][1] = y1r*s4 + y1i*c4;
    const float y2r = t0r - t2r, y2i = t0i - t2i;
    fRr[a][2] = y2r*c8 - y2i*s8;    fRi[a][2] = y2r*s8 + y2i*c8;
    const float y3r = t1r - t3i, y3i = t1i + t3r;
    fRr[a][3] = y3r*c12 - y3i*s12;  fRi[a][3] = y3r*s12 + y3i*c12;
  }

  // ---- transpose 1 through 512-complex buffer, two wave-synchronous phases ----
  const int g = t >> 2, cc = t & 3;
  float yrr[4][4], yii[4][4];
  // phase A: write locations [0,512) (a=0,1); readers g<8 (t<32)
#pragma unroll
  for (int a = 0; a < 2; ++a)
#pragma unroll
    for (int b = 0; b < 4; ++b)
      buf[FL(((a*4+b) << 6) + t)] = make_float2(fRr[a][b], fRi[a][b]);
  if (t < 32) {
    const int gb = g << 6;
#pragma unroll
    for (int u = 0; u < 4; ++u)
#pragma unroll
      for (int v = 0; v < 4; ++v) {
        const float2 z = buf[FL(gb + u*16 + v*4 + cc)];
        yrr[u][v] = z.x; yii[u][v] = z.y;
      }
  }
  // phase B: overwrite with locations [512,1024) (a=2,3); readers g>=8
#pragma unroll
  for (int a = 2; a < 4; ++a)
#pragma unroll
    for (int b = 0; b < 4; ++b)
      buf[FL((((a-2)*4+b) << 6) + t)] = make_float2(fRr[a][b], fRi[a][b]);
  if (t >= 32) {
    const int gb = (g - 8) << 6;
#pragma unroll
    for (int u = 0; u < 4; ++u)
#pragma unroll
      for (int v = 0; v < 4; ++v) {
        const float2 z = buf[FL(gb + u*16 + v*4 + cc)];
        yrr[u][v] = z.x; yii[u][v] = z.y;
      }
  }

  // ---- FFT stage 3 (LEN=64) ----
  const float angc = -0.09817477042468103f * (float)cc;
  const float wc1r = __cosf(angc), wc1i = __sinf(angc);
#pragma unroll
  for (int v = 0; v < 4; ++v) {
    const float t1r_ = wc1r*OB1r[v] - wc1i*OB1i[v];
    const float t1i_ = wc1r*OB1i[v] + wc1i*OB1r[v];
    const float t2r_ = t1r_*t1r_ - t1i_*t1i_;
    const float t2i_ = 2.f*t1r_*t1i_;
    const float t3r_ = t1r_*t2r_ - t1i_*t2i_;
    const float t3i_ = t1i_*t2r_ + t1r_*t2i_;
    const float A0r=yrr[0][v], A0i=yii[0][v], A1r=yrr[1][v], A1i=yii[1][v];
    const float A2r=yrr[2][v], A2i=yii[2][v], A3r=yrr[3][v], A3i=yii[3][v];
    const float t0r=A0r+A2r, t0i=A0i+A2i, t1r=A0r-A2r, t1i=A0i-A2i;
    const float t2r=A1r+A3r, t2i=A1i+A3i, t3r=A1r-A3r, t3i=A1i-A3i;
    yrr[0][v] = t0r + t2r;  yii[0][v] = t0i + t2i;
    const float y1r = t1r + t3i, y1i = t1i - t3r;
    yrr[1][v] = y1r*t1r_ - y1i*t1i_;  yii[1][v] = y1r*t1i_ + y1i*t1r_;
    const float y2r = t0r - t2r, y2i = t0i - t2i;
    yrr[2][v] = y2r*t2r_ - y2i*t2i_;  yii[2][v] = y2r*t2i_ + y2i*t2r_;
    const float y3r = t1r - t3i, y3i = t1i + t3r;
    yrr[3][v] = y3r*t3r_ - y3i*t3i_;  yii[3][v] = y3r*t3i_ + y3i*t3r_;
  }

  // ---- FFT stage 4 (LEN=16) ----
  const float q2r = wc1r*wc1r - wc1i*wc1i, q2i = 2.f*wc1r*wc1i;
  const float w4r = q2r*q2r - q2i*q2i,     w4i = 2.f*q2r*q2i;
  const float w8r = w4r*w4r - w4i*w4i,     w8i = 2.f*w4r*w4i;
  const float w12r = w4r*w8r - w4i*w8i,    w12i = w4i*w8r + w4r*w8i;
#pragma unroll
  for (int u = 0; u < 4; ++u) {
    const float A0r=yrr[u][0], A0i=yii[u][0], A1r=yrr[u][1], A1i=yii[u][1];
    const float A2r=yrr[u][2], A2i=yii[u][2], A3r=yrr[u][3], A3i=yii[u][3];
    const float t0r=A0r+A2r, t0i=A0i+A2i, t1r=A0r-A2r, t1i=A0i-A2i;
    const float t2r=A1r+A3r, t2i=A1i+A3i, t3r=A1r-A3r, t3i=A1i-A3i;
    yrr[u][0] = t0r + t2r;  yii[u][0] = t0i + t2i;
    const float y1r = t1r + t3i, y1i = t1i - t3r;
    yrr[u][1] = y1r*w4r - y1i*w4i;    yii[u][1] = y1r*w4i + y1i*w4r;
    const float y2r = t0r - t2r, y2i = t0i - t2i;
    yrr[u][2] = y2r*w8r - y2i*w8i;    yii[u][2] = y2r*w8i + y2i*w8r;
    const float y3r = t1r - t3i, y3i = t1i + t3r;
    yrr[u][3] = y3r*w12r - y3i*w12i;  yii[u][3] = y3r*w12i + y3i*w12r;
  }

  // ---- transpose 2 + fused final stage + psd, compact half-spectrum passes ----
  // compact addr = 32g + 16*u' + 4v + cc, u' = u or u-2.  Readers: every lane
  // takes 8 values (2 complete cc-quads) per pass: base = 32*(t>>2)+16*((t>>1)&1)+8*(t&1).
  float psum = 0.f, pmax = 0.f, plog = 0.f;
  const int cb = 32*g + cc;
  const int base = 32*(t>>2) + 16*((t>>1)&1) + 8*(t&1);

  auto psd_quad = [&](int bix){
    const float2 z0 = buf[FL(bix+0)], z1 = buf[FL(bix+1)], z2 = buf[FL(bix+2)], z3 = buf[FL(bix+3)];
    const float t0r=z0.x+z2.x, t0i=z0.y+z2.y, t1r=z0.x-z2.x, t1i=z0.y-z2.y;
    const float t2r=z1.x+z3.x, t2i=z1.y+z3.y, t3r=z1.x-z3.x, t3i=z1.y-z3.y;
    const float y0r=t0r+t2r, y0i=t0i+t2i;
    const float y1r=t1r+t3i, y1i=t1i-t3r;
    const float y2r=t0r-t2r, y2i=t0i-t2i;
    const float y3r=t1r-t3i, y3i=t1i+t3r;
    const float pp0 = fmaxf(y0r*y0r + y0i*y0i, EPSF);
    const float pp1 = fmaxf(y1r*y1r + y1i*y1i, EPSF);
    const float pp2 = fmaxf(y2r*y2r + y2i*y2i, EPSF);
    const float pp3 = fmaxf(y3r*y3r + y3i*y3i, EPSF);
    psum += pp0 + pp1 + pp2 + pp3;
    pmax = fmaxf(fmaxf(pmax, pp0), fmaxf(pp1, pp2));
    pmax = fmaxf(pmax, pp3);
    plog += pp0*__logf(pp0) + pp1*__logf(pp1) + pp2*__logf(pp2) + pp3*__logf(pp3);
  };

  // pass A: u = 0,1
#pragma unroll
  for (int u = 0; u < 2; ++u)
#pragma unroll
    for (int v = 0; v < 4; ++v)
      buf[FL(cb + 16*u + 4*v)] = make_float2(yrr[u][v], yii[u][v]);
  psd_quad(base);
  psd_quad(base + 4);
  // pass B: u = 2,3 (same compact slots; reads of pass A already retired in order)
#pragma unroll
  for (int u = 2; u < 4; ++u)
#pragma unroll
    for (int v = 0; v < 4; ++v)
      buf[FL(cb + 16*(u-2) + 4*v)] = make_float2(yrr[u][v], yii[u][v]);
  psd_quad(base);
  psd_quad(base + 4);

  const float PSUM = rl(wave_red_add(psum), 63);
  const float PMAX = rl(wave_red_max_pos(pmax), 63);
  const float PLOG = rl(wave_red_add(plog), 63);

  // ---- stashed uniform stats ----
  const float SUMSQ = st[0];
  const float ALT   = st[1];
  const float STR   = st[12];
  const float STR2  = st[13];
  const float SC    = st[14];
  const float SC2   = st[15];
  const float SUMX  = st[16];
  const float x0    = st[37];
  const float xl    = st[38];

  // ---- features ----
  const float p0b   = fmaxf(SUMX * SUMX, EPSF);
  const float p512b = fmaxf(ALT * ALT, EPSF);
  const float Sr    = 0.5f * (PSUM + p0b + p512b);
  const float invS  = 1.f / Sr;
  const float PLr   = 0.5f * (PLOG + p0b*__logf(p0b) + p512b*__logf(p512b));
  const float ent   = __logf(Sr) - PLr * invS;

  const float m = SUMX * (1.f / 1024.f);
  const float den = SUMSQ - 1024.f * m * m + EPSF;
  const float invden = 1.f / den;
  float acf1 = 0.f, acf2 = 0.f, lbq = 0.f, R1v = 0.f;
#pragma unroll
  for (int k = 1; k <= 10; ++k) {
    const float Rkv = st[1 + k];
    const float Slo = st[16 + k];
    const float Shi = st[37 - k];
    const float num = Rkv - m * (Shi + (SUMX - Slo)) + (float)(1024 - k) * m * m;
    const float a = fminf(fmaxf(num * invden, -1.f), 1.f);
    if (k == 1) { acf1 = a; R1v = Rkv; }
    else if (k == 2) acf2 = a;
    lbq += a * a;
  }
  const float spent = fminf(fmaxf(ent / (__logf(513.f + EPSF) + EPSF), 0.f), 1.f);
  const float peak  = fminf(fmaxf(PMAX / (Sr + EPSF), 0.f), 1.f);
  const float phi = fminf(fmaxf(R1v / ((SUMSQ - xl * xl) + EPSF), -1.f), 1.f);
  const float invn = 1.f / 1023.f;
  const float sum_d2 = 2.f * SUMSQ - x0 * x0 - xl * xl - 2.f * R1v;
  const float md = (xl - x0) * invn;
  const float diff_var = sum_d2 * invn - md * md;
  const float tstr = STR2 * (1.f / 1024.f) - (STR * (1.f / 1024.f)) * (STR * (1.f / 1024.f));
  const float varx = SUMSQ * (1.f / 1024.f) - m * m;
  const float mc = SC * (1.f / 1024.f);
  const float kpss = (SC2 * (1.f / 1024.f) - mc * mc) / (varx + 1e-8f);

  float f[9] = {acf1, acf2, spent, phi, diff_var, tstr, kpss, lbq, peak};
  float fm = 0.f;
#pragma unroll
  for (int d = 0; d < 9; ++d) fm += f[d];
  fm *= (1.f / 9.f);
  float fv = 0.f;
#pragma unroll
  for (int d = 0; d < 9; ++d) { const float tt = f[d] - fm; fv = fmaf(tt, tt, fv); }
  fv *= (1.f / 9.f);
  const float inl = 1.f / sqrtf(fv + 1e-5f);
  float fn[9];
#pragma unroll
  for (int d = 0; d < 9; ++d) fn[d] = (f[d] - fm) * inl * ln_w[d] + ln_b[d];

  // ---- MLP: hidden unit = lane ----
  float h = b1[t];
#pragma unroll
  for (int d = 0; d < 9; ++d) h = fmaf(fn[d], w1[d * 64 + t], h);
  h = fmaxf(h, 0.f);
  float l0 = h * w2[t * 3 + 0];
  float l1 = h * w2[t * 3 + 1];
  float l2 = h * w2[t * 3 + 2];
  l0 = wave_red_add(l0);
  l1 = wave_red_add(l1);
  l2 = wave_red_add(l2);
  const float L0 = rl(l0, 63) + b2[0];
  const float L1 = rl(l1, 63) + b2[1];
  const float L2 = rl(l2, 63) + b2[2];
  if (t == 0) {
    const float mx = fmaxf(L0, fmaxf(L1, L2));
    const float e0 = __expf(L0 - mx), e1 = __expf(L1 - mx), e2 = __expf(L2 - mx);
    const float is = 1.f / (e0 + e1 + e2);
    float* o = out + (size_t)row * 3;
    o[0] = e0 * is; o[1] = e1 * is; o[2] = e2 * is;
    float* fo = out + (size_t)B * 3 + (size_t)row * 9;
    fo[0] = fn[0]; fo[1] = fn[1]; fo[2] = fn[2]; fo[3] = fn[3]; fo[4] = fn[4];
    fo[5] = fn[5]; fo[6] = fn[6]; fo[7] = fn[7]; fo[8] = fn[8];
  }
}

extern "C" void kernel_launch(void* const* d_in, const int* in_sizes, int n_in,
                              void* d_out, int out_size, void* d_ws, size_t ws_size,
                              hipStream_t stream) {
  (void)n_in; (void)out_size; (void)d_ws; (void)ws_size;
  const float* x    = (const float*)d_in[0];
  const float* ln_w = (const float*)d_in[1];
  const float* ln_b = (const float*)d_in[2];
  const float* w1   = (const float*)d_in[3];
  const float* b1   = (const float*)d_in[4];
  const float* w2   = (const float*)d_in[5];
  const float* b2   = (const float*)d_in[6];
  float* out = (float*)d_out;
  const int B = in_sizes[0] / 1024;
  sr_kernel<<<(B + 1) / 2, 128, 0, stream>>>(x, ln_w, ln_b, w1, b1, w2, b2, out, B);
}

// Round 9
// 95.399 us; speedup vs baseline: 1.2310x; 1.2310x over previous
//
#include <hip/hip_runtime.h>
#include <math.h>

#define EPSF 1e-8f

typedef float f2v __attribute__((ext_vector_type(2)));

__device__ __forceinline__ float bcf(int x){ return __builtin_bit_cast(float, x); }
__device__ __forceinline__ int   bci(float x){ return __builtin_bit_cast(int, x); }

template<int CTRL, int RM>
__device__ __forceinline__ float dpp0(float v){
  return bcf(__builtin_amdgcn_update_dpp(0, bci(v), CTRL, RM, 0xF, false));
}
__device__ __forceinline__ float rl(float v, int l){
  return bcf(__builtin_amdgcn_readlane(bci(v), l));
}
__device__ __forceinline__ float wave_iscan_add(float v){
  v += dpp0<0x111,0xF>(v);
  v += dpp0<0x112,0xF>(v);
  v += dpp0<0x114,0xF>(v);
  v += dpp0<0x118,0xF>(v);
  v += dpp0<0x142,0xA>(v);
  v += dpp0<0x143,0xC>(v);
  return v;
}
__device__ __forceinline__ float wave_red_add(float v){ return wave_iscan_add(v); } // lane63 = total
__device__ __forceinline__ float wave_red_max_pos(float v){ // v >= 0
  v = fmaxf(v, dpp0<0x111,0xF>(v));
  v = fmaxf(v, dpp0<0x112,0xF>(v));
  v = fmaxf(v, dpp0<0x114,0xF>(v));
  v = fmaxf(v, dpp0<0x118,0xF>(v));
  v = fmaxf(v, dpp0<0x142,0xA>(v));
  v = fmaxf(v, dpp0<0x143,0xC>(v));
  return v;
}

// Swizzle for the 512-complex buffer: slot = low4 ^ q ^ ((q&1)<<3), q = i>>6.
// Hand-verified at the 4-lane/slot b64 floor for all 8 access patterns
// (T1 w/r, T2 w/r, untangle w/r).
__device__ __forceinline__ int FLS(int i){
  const int q = (i >> 6) & 7;
  return i ^ q ^ ((q & 1) << 3);
}

// In-place 8-point complex DFT (DIT inside): ~56 real ops, output index = bin q.
__device__ __forceinline__ void dft8(float* ar, float* ai){
  constexpr float C = 0.70710678118654752f;
  const float t0r=ar[0]+ar[4], t0i=ai[0]+ai[4];
  const float t1r=ar[0]-ar[4], t1i=ai[0]-ai[4];
  const float t2r=ar[2]+ar[6], t2i=ai[2]+ai[6];
  const float t3r=ar[2]-ar[6], t3i=ai[2]-ai[6];
  const float E0r=t0r+t2r, E0i=t0i+t2i;
  const float E1r=t1r+t3i, E1i=t1i-t3r;
  const float E2r=t0r-t2r, E2i=t0i-t2i;
  const float E3r=t1r-t3i, E3i=t1i+t3r;
  const float u0r=ar[1]+ar[5], u0i=ai[1]+ai[5];
  const float u1r=ar[1]-ar[5], u1i=ai[1]-ai[5];
  const float u2r=ar[3]+ar[7], u2i=ai[3]+ai[7];
  const float u3r=ar[3]-ar[7], u3i=ai[3]-ai[7];
  const float O0r=u0r+u2r, O0i=u0i+u2i;
  const float O1r=u1r+u3i, O1i=u1i-u3r;
  const float O2r=u0r-u2r, O2i=u0i-u2i;
  const float O3r=u1r-u3i, O3i=u1i+u3r;
  const float w1r =  C*(O1r+O1i), w1i = C*(O1i-O1r);   // w8^1 * O1
  const float w2r =  O2i,         w2i = -O2r;          // -i * O2
  const float w3r =  C*(O3i-O3r), w3i = -C*(O3r+O3i);  // w8^3 * O3
  ar[0]=E0r+O0r; ai[0]=E0i+O0i;
  ar[4]=E0r-O0r; ai[4]=E0i-O0i;
  ar[1]=E1r+w1r; ai[1]=E1i+w1i;
  ar[5]=E1r-w1r; ai[5]=E1i-w1i;
  ar[2]=E2r+w2r; ai[2]=E2i+w2i;
  ar[6]=E2r-w2r; ai[6]=E2i-w2i;
  ar[3]=E3r+w3r; ai[3]=E3i+w3i;
  ar[7]=E3r-w3r; ai[7]=E3i-w3i;
}

// stats LDS slots (per wave): 0 SUMSQ, 1 ALT, 2..11 R1..R10, 12 STR, 13 STR2,
// 14 SC, 15 SC2, 16 SUMX, 17..26 Slo, 27..36 Shi pool, 37 x0, 38 xl
__global__ void __launch_bounds__(128, 2)
sr_kernel(const float* __restrict__ x,
          const float* __restrict__ ln_w, const float* __restrict__ ln_b,
          const float* __restrict__ w1, const float* __restrict__ b1,
          const float* __restrict__ w2, const float* __restrict__ b2,
          float* __restrict__ out, int B)
{
  __shared__ __align__(16) float2 buf2[2][512];     // 4KB per wave
  __shared__ __align__(16) float stats2[2][40];

  const int tid = threadIdx.x;
  const int t   = tid & 63;
  const int wv  = tid >> 6;
  const int row = blockIdx.x * 2 + wv;
  if (row >= B) return;
  const float* __restrict__ xr = x + (size_t)row * 1024;
  float2* buf = buf2[wv];
  float*  st  = stats2[wv];

  // ---- loads: own 16 + 12 right + 12 left neighbors ----
  const int c0 = t * 16;
  float vv[28];
  {
    const float4 a0 = *reinterpret_cast<const float4*>(xr + c0);
    const float4 a1 = *reinterpret_cast<const float4*>(xr + c0 + 4);
    const float4 a2 = *reinterpret_cast<const float4*>(xr + c0 + 8);
    const float4 a3 = *reinterpret_cast<const float4*>(xr + c0 + 12);
    vv[0]=a0.x; vv[1]=a0.y; vv[2]=a0.z; vv[3]=a0.w;
    vv[4]=a1.x; vv[5]=a1.y; vv[6]=a1.z; vv[7]=a1.w;
    vv[8]=a2.x; vv[9]=a2.y; vv[10]=a2.z; vv[11]=a2.w;
    vv[12]=a3.x; vv[13]=a3.y; vv[14]=a3.z; vv[15]=a3.w;
    if (t < 63) {
      const float4 n0 = *reinterpret_cast<const float4*>(xr + c0 + 16);
      const float4 n1 = *reinterpret_cast<const float4*>(xr + c0 + 20);
      const float4 n2 = *reinterpret_cast<const float4*>(xr + c0 + 24);
      vv[16]=n0.x; vv[17]=n0.y; vv[18]=n0.z; vv[19]=n0.w;
      vv[20]=n1.x; vv[21]=n1.y; vv[22]=n1.z; vv[23]=n1.w;
      vv[24]=n2.x; vv[25]=n2.y; vv[26]=n2.z; vv[27]=n2.w;
    } else {
#pragma unroll
      for (int j = 16; j < 28; ++j) vv[j] = 0.f;
    }
  }
  float pv[12];
  if (t > 0) {
    const float4 p0 = *reinterpret_cast<const float4*>(xr + c0 - 12);
    const float4 p1 = *reinterpret_cast<const float4*>(xr + c0 - 8);
    const float4 p2 = *reinterpret_cast<const float4*>(xr + c0 - 4);
    pv[0]=p0.x; pv[1]=p0.y; pv[2]=p0.z; pv[3]=p0.w;
    pv[4]=p1.x; pv[5]=p1.y; pv[6]=p1.z; pv[7]=p1.w;
    pv[8]=p2.x; pv[9]=p2.y; pv[10]=p2.z; pv[11]=p2.w;
  } else {
#pragma unroll
    for (int j = 0; j < 12; ++j) pv[j] = 0.f;
  }

  // ---- per-thread stats ----
  {
    f2v sq2 = {0.f, 0.f}, al2 = {0.f, 0.f};
#pragma unroll
    for (int j = 0; j < 16; j += 2) {
      f2v a = {vv[j], vv[j+1]};
      sq2 += a * a;
      al2 += a;
    }
    float r;
    r = wave_red_add(sq2.x + sq2.y); if (t == 63) st[0] = r;
    r = wave_red_add(al2.x - al2.y); if (t == 63) st[1] = r;
  }
#pragma unroll
  for (int k = 1; k <= 10; ++k) {
    f2v acc = {0.f, 0.f};
#pragma unroll
    for (int j = 0; j < 16; j += 2) {
      f2v a = {vv[j], vv[j+1]};
      f2v b = {vv[j+k], vv[j+k+1]};
      acc += a * b;
    }
    float r = wave_red_add(acc.x + acc.y);
    if (t == 63) st[1 + k] = r;
  }

  // ---- prefix sums ----
  float s[16];
  s[0] = vv[0];
#pragma unroll
  for (int j = 1; j < 16; ++j) s[j] = s[j-1] + vv[j];
  const float cs16 = s[15];
  const float incl = wave_iscan_add(cs16);
  const float excl = incl - cs16;
#pragma unroll
  for (int j = 0; j < 16; ++j) s[j] += excl;
  if (t == 63) st[16] = incl;                       // SUMX
  if (t == 0) {
#pragma unroll
    for (int q = 0; q < 10; ++q) st[17 + q] = s[q];
    st[37] = vv[0];
  }
  if (t == 63) {
#pragma unroll
    for (int q = 0; q < 10; ++q) st[27 + q] = s[5 + q];
    st[38] = vv[15];
  }

  // ---- trend via sliding +-12 window ----
  float trv[16];
  float str = 0.f, str2 = 0.f;
  {
    float wsum = 0.f;
#pragma unroll
    for (int j = 0; j < 12; ++j) wsum += pv[j];
#pragma unroll
    for (int j = 0; j <= 12; ++j) wsum += vv[j];
#pragma unroll
    for (int jj = 0; jj < 16; ++jj) {
      if (jj > 0) {
        const float addv = vv[jj + 12];
        const float subv = (jj < 13) ? pv[jj - 1] : vv[jj - 13];
        wsum += addv - subv;
      }
      float swc = wsum;
      if (t == 0  && jj < 12) swc += (float)(12 - jj) * vv[0];
      if (t == 63 && jj >= 4) swc += (float)(jj - 3) * vv[15];
      const float tv = swc * 0.04f;
      trv[jj] = tv;
      str += tv;
      str2 = fmaf(tv, tv, str2);
    }
  }
  const float tincl = wave_iscan_add(str);
  if (t == 63) st[12] = tincl;
  { float r = wave_red_add(str2); if (t == 63) st[13] = r; }
  {
    const float texcl = tincl - str;
    float run = texcl, sc = 0.f, sc2 = 0.f;
#pragma unroll
    for (int jj = 0; jj < 16; ++jj) {
      run += trv[jj];
      const float cv = s[jj] - run;
      sc += cv;
      sc2 = fmaf(cv, cv, sc2);
    }
    float r;
    r = wave_red_add(sc);  if (t == 63) st[14] = r;
    r = wave_red_add(sc2); if (t == 63) st[15] = r;
  }

  // ==================== half-length real FFT: Z = FFT_512(x[2m] + i x[2m+1]) ====================
  float zr[8], zi[8];
  // stage A: c = t, a_p = z[t + 64p]; loads are 8B float2 (lane-contiguous 512B)
#pragma unroll
  for (int p = 0; p < 8; ++p) {
    const float2 v = *reinterpret_cast<const float2*>(xr + 2*t + 128*p);
    zr[p] = v.x; zi[p] = v.y;
  }
  dft8(zr, zi);
  {
    // twiddles W512^{t q}, q=1..7 via recurrence from 2 trans ops
    const float a1 = -0.012271846303085130f * (float)t;   // -2pi/512 * t
    const float c1 = __cosf(a1), s1 = __sinf(a1);
    const float c2=c1*c1-s1*s1, s2=2.f*c1*s1;
    const float c3=c2*c1-s2*s1, s3=s2*c1+c2*s1;
    const float c4=c2*c2-s2*s2, s4=2.f*c2*s2;
    const float c5=c4*c1-s4*s1, s5=s4*c1+c4*s1;
    const float c6=c3*c3-s3*s3, s6=2.f*c3*s3;
    const float c7=c6*c1-s6*s1, s7=s6*c1+c6*s1;
    const float cq[8] = {1.f,c1,c2,c3,c4,c5,c6,c7};
    const float sq[8] = {0.f,s1,s2,s3,s4,s5,s6,s7};
#pragma unroll
    for (int q = 1; q < 8; ++q) {
      const float r0 = zr[q]*cq[q] - zi[q]*sq[q];
      zi[q] = zr[q]*sq[q] + zi[q]*cq[q];
      zr[q] = r0;
    }
  }
  // transpose 1: w_q stored at q*64 + c
#pragma unroll
  for (int q = 0; q < 8; ++q)
    buf[FLS(q*64 + t)] = make_float2(zr[q], zi[q]);
  const int qq = t >> 3;         // this thread's subproblem q (stages B/C)
  const int dd = t & 7;          // stage-B d; doubles as stage-C s label
  const int qb = qq << 6;
#pragma unroll
  for (int e = 0; e < 8; ++e) {
    const float2 z = buf[FLS(qb + dd + 8*e)];
    zr[e] = z.x; zi[e] = z.y;
  }
  dft8(zr, zi);
  {
    // twiddles W64^{d s}, s=1..7
    const float a1 = -0.098174770424681039f * (float)dd;  // -2pi/64 * d
    const float c1 = __cosf(a1), s1 = __sinf(a1);
    const float c2=c1*c1-s1*s1, s2=2.f*c1*s1;
    const float c3=c2*c1-s2*s1, s3=s2*c1+c2*s1;
    const float c4=c2*c2-s2*s2, s4=2.f*c2*s2;
    const float c5=c4*c1-s4*s1, s5=s4*c1+c4*s1;
    const float c6=c3*c3-s3*s3, s6=2.f*c3*s3;
    const float c7=c6*c1-s6*s1, s7=s6*c1+c6*s1;
    const float cq[8] = {1.f,c1,c2,c3,c4,c5,c6,c7};
    const float sq[8] = {0.f,s1,s2,s3,s4,s5,s6,s7};
#pragma unroll
    for (int q = 1; q < 8; ++q) {
      const float r0 = zr[q]*cq[q] - zi[q]*sq[q];
      zi[q] = zr[q]*sq[q] + zi[q]*cq[q];
      zr[q] = r0;
    }
  }
  // transpose 2: v_{q,s}[d] stored at q*64 + s*8 + d
#pragma unroll
  for (int sA = 0; sA < 8; ++sA)
    buf[FLS(qb + sA*8 + dd)] = make_float2(zr[sA], zi[sA]);
#pragma unroll
  for (int d = 0; d < 8; ++d) {
    const float2 z = buf[FLS(qb + dd*8 + d)];
    zr[d] = z.x; zi[d] = z.y;
  }
  dft8(zr, zi);
  // now register r holds Z[k], k = 64r + 8*dd + qq

  // ---- untangle to rfft psd: write Z, read conjugate partner ----
#pragma unroll
  for (int r = 0; r < 8; ++r)
    buf[FLS(t*8 + r)] = make_float2(zr[r], zi[r]);
  const int pl = (t == 0) ? 0 : ((t < 8) ? (8 - t) : (71 - t));
  const bool lane0 = (t == 0);
  // W_k = e^{-i pi k/512} = wb * e^{-i pi r/8}
  const float kb = (float)((dd << 3) + qq);
  const float ab = -0.0061359231515425649f * kb;          // -pi/512 * (8s+q)
  const float wbr = __cosf(ab), wbi = __sinf(ab);
  constexpr float RCr[8] = {1.f, 0.98078528040323044f, 0.92387953251128674f, 0.83146961230254524f,
                            0.70710678118654752f, 0.55557023301960222f, 0.38268343236508977f, 0.19509032201612827f};
  constexpr float RCi[8] = {0.f, -0.19509032201612827f, -0.38268343236508977f, -0.55557023301960222f,
                            -0.70710678118654752f, -0.83146961230254524f, -0.92387953251128674f, -0.98078528040323044f};
  float psum = 0.f, pmax = 0.f, plog = 0.f;
#pragma unroll
  for (int r = 0; r < 8; ++r) {
    const int rho = lane0 ? ((8 - r) & 7) : (7 - r);
    const float2 zp = buf[FLS(pl*8 + rho)];
    const float Er = 0.5f*(zr[r] + zp.x);
    const float Ei = 0.5f*(zi[r] - zp.y);
    const float Or = 0.5f*(zi[r] + zp.y);
    const float Oi = -0.5f*(zr[r] - zp.x);
    const float wr = wbr*RCr[r] - wbi*RCi[r];
    const float wi = wbr*RCi[r] + wbi*RCr[r];
    const float Xr = Er + wr*Or - wi*Oi;
    const float Xi = Ei + wr*Oi + wi*Or;
    const float pp = fmaxf(Xr*Xr + Xi*Xi, EPSF);
    psum += pp;
    pmax = fmaxf(pmax, pp);
    plog += pp * __logf(pp);
  }
  const float PSUM = rl(wave_red_add(psum), 63);
  const float PMAX = rl(wave_red_max_pos(pmax), 63);
  const float PLOG = rl(wave_red_add(plog), 63);

  // ---- stashed uniform stats ----
  const float SUMSQ = st[0];
  const float ALT   = st[1];
  const float STR   = st[12];
  const float STR2  = st[13];
  const float SC    = st[14];
  const float SC2   = st[15];
  const float SUMX  = st[16];
  const float x0    = st[37];
  const float xl    = st[38];

  // ---- features (bins 0..511 are in PSUM/PLOG/PMAX; bin 512 = ALT^2 added here) ----
  const float p512b = fmaxf(ALT * ALT, EPSF);
  const float Sr    = PSUM + p512b;
  const float invS  = 1.f / Sr;
  const float PLr   = PLOG + p512b * __logf(p512b);
  const float ent   = __logf(Sr) - PLr * invS;
  const float PMX   = fmaxf(PMAX, p512b);

  const float m = SUMX * (1.f / 1024.f);
  const float den = SUMSQ - 1024.f * m * m + EPSF;
  const float invden = 1.f / den;
  float acf1 = 0.f, acf2 = 0.f, lbq = 0.f, R1v = 0.f;
#pragma unroll
  for (int k = 1; k <= 10; ++k) {
    const float Rkv = st[1 + k];
    const float Slo = st[16 + k];
    const float Shi = st[37 - k];
    const float num = Rkv - m * (Shi + (SUMX - Slo)) + (float)(1024 - k) * m * m;
    const float a = fminf(fmaxf(num * invden, -1.f), 1.f);
    if (k == 1) { acf1 = a; R1v = Rkv; }
    else if (k == 2) acf2 = a;
    lbq += a * a;
  }
  const float spent = fminf(fmaxf(ent / (__logf(513.f + EPSF) + EPSF), 0.f), 1.f);
  const float peak  = fminf(fmaxf(PMX / (Sr + EPSF), 0.f), 1.f);
  const float phi = fminf(fmaxf(R1v / ((SUMSQ - xl * xl) + EPSF), -1.f), 1.f);
  const float invn = 1.f / 1023.f;
  const float sum_d2 = 2.f * SUMSQ - x0 * x0 - xl * xl - 2.f * R1v;
  const float md = (xl - x0) * invn;
  const float diff_var = sum_d2 * invn - md * md;
  const float tstr = STR2 * (1.f / 1024.f) - (STR * (1.f / 1024.f)) * (STR * (1.f / 1024.f));
  const float varx = SUMSQ * (1.f / 1024.f) - m * m;
  const float mc = SC * (1.f / 1024.f);
  const float kpss = (SC2 * (1.f / 1024.f) - mc * mc) / (varx + 1e-8f);

  float f[9] = {acf1, acf2, spent, phi, diff_var, tstr, kpss, lbq, peak};
  float fm = 0.f;
#pragma unroll
  for (int d = 0; d < 9; ++d) fm += f[d];
  fm *= (1.f / 9.f);
  float fv = 0.f;
#pragma unroll
  for (int d = 0; d < 9; ++d) { const float tt = f[d] - fm; fv = fmaf(tt, tt, fv); }
  fv *= (1.f / 9.f);
  const float inl = 1.f / sqrtf(fv + 1e-5f);
  float fn[9];
#pragma unroll
  for (int d = 0; d < 9; ++d) fn[d] = (f[d] - fm) * inl * ln_w[d] + ln_b[d];

  // ---- MLP: hidden unit = lane ----
  float h = b1[t];
#pragma unroll
  for (int d = 0; d < 9; ++d) h = fmaf(fn[d], w1[d * 64 + t], h);
  h = fmaxf(h, 0.f);
  float l0 = h * w2[t * 3 + 0];
  float l1 = h * w2[t * 3 + 1];
  float l2 = h * w2[t * 3 + 2];
  l0 = wave_red_add(l0);
  l1 = wave_red_add(l1);
  l2 = wave_red_add(l2);
  const float L0 = rl(l0, 63) + b2[0];
  const float L1 = rl(l1, 63) + b2[1];
  const float L2 = rl(l2, 63) + b2[2];
  if (t == 0) {
    const float mx = fmaxf(L0, fmaxf(L1, L2));
    const float e0 = __expf(L0 - mx), e1 = __expf(L1 - mx), e2 = __expf(L2 - mx);
    const float is = 1.f / (e0 + e1 + e2);
    float* o = out + (size_t)row * 3;
    o[0] = e0 * is; o[1] = e1 * is; o[2] = e2 * is;
    float* fo = out + (size_t)B * 3 + (size_t)row * 9;
    fo[0] = fn[0]; fo[1] = fn[1]; fo[2] = fn[2]; fo[3] = fn[3]; fo[4] = fn[4];
    fo[5] = fn[5]; fo[6] = fn[6]; fo[7] = fn[7]; fo[8] = fn[8];
  }
}

extern "C" void kernel_launch(void* const* d_in, const int* in_sizes, int n_in,
                              void* d_out, int out_size, void* d_ws, size_t ws_size,
                              hipStream_t stream) {
  (void)n_in; (void)out_size; (void)d_ws; (void)ws_size;
  const float* x    = (const float*)d_in[0];
  const float* ln_w = (const float*)d_in[1];
  const float* ln_b = (const float*)d_in[2];
  const float* w1   = (const float*)d_in[3];
  const float* b1   = (const float*)d_in[4];
  const float* w2   = (const float*)d_in[5];
  const float* b2   = (const float*)d_in[6];
  float* out = (float*)d_out;
  const int B = in_sizes[0] / 1024;
  sr_kernel<<<(B + 1) / 2, 128, 0, stream>>>(x, ln_w, ln_b, w1, b1, w2, b2, out, B);
}

// Round 10
// 91.735 us; speedup vs baseline: 1.2801x; 1.0399x over previous
//
#include <hip/hip_runtime.h>
#include <math.h>

#define EPSF 1e-8f

__device__ __forceinline__ float bcf(int x){ return __builtin_bit_cast(float, x); }
__device__ __forceinline__ int   bci(float x){ return __builtin_bit_cast(int, x); }

template<int CTRL, int RM>
__device__ __forceinline__ float dpp0(float v){
  return bcf(__builtin_amdgcn_update_dpp(0, bci(v), CTRL, RM, 0xF, false));
}
__device__ __forceinline__ float rl(float v, int l){
  return bcf(__builtin_amdgcn_readlane(bci(v), l));
}
__device__ __forceinline__ float wave_iscan_add(float v){
  v += dpp0<0x111,0xF>(v);
  v += dpp0<0x112,0xF>(v);
  v += dpp0<0x114,0xF>(v);
  v += dpp0<0x118,0xF>(v);
  v += dpp0<0x142,0xA>(v);
  v += dpp0<0x143,0xC>(v);
  return v;
}
__device__ __forceinline__ float wave_red_add(float v){ return wave_iscan_add(v); } // lane63 = total
__device__ __forceinline__ float wave_red_max_pos(float v){ // v >= 0
  v = fmaxf(v, dpp0<0x111,0xF>(v));
  v = fmaxf(v, dpp0<0x112,0xF>(v));
  v = fmaxf(v, dpp0<0x114,0xF>(v));
  v = fmaxf(v, dpp0<0x118,0xF>(v));
  v = fmaxf(v, dpp0<0x142,0xA>(v));
  v = fmaxf(v, dpp0<0x143,0xC>(v));
  return v;
}

// Swizzle for the 512-complex buffer: slot = low4 ^ q ^ ((q&1)<<3), q = i>>6.
// All access patterns verified at the 4-lane/slot b64 floor
// (z-write 8t+j, z-read t+64p, T1 w/r, T2 w/r, untangle w/r).
__device__ __forceinline__ int FLS(int i){
  const int q = (i >> 6) & 7;
  return i ^ q ^ ((q & 1) << 3);
}

// In-place 8-point complex DFT.
__device__ __forceinline__ void dft8(float* ar, float* ai){
  constexpr float C = 0.70710678118654752f;
  const float t0r=ar[0]+ar[4], t0i=ai[0]+ai[4];
  const float t1r=ar[0]-ar[4], t1i=ai[0]-ai[4];
  const float t2r=ar[2]+ar[6], t2i=ai[2]+ai[6];
  const float t3r=ar[2]-ar[6], t3i=ai[2]-ai[6];
  const float E0r=t0r+t2r, E0i=t0i+t2i;
  const float E1r=t1r+t3i, E1i=t1i-t3r;
  const float E2r=t0r-t2r, E2i=t0i-t2i;
  const float E3r=t1r-t3i, E3i=t1i+t3r;
  const float u0r=ar[1]+ar[5], u0i=ai[1]+ai[5];
  const float u1r=ar[1]-ar[5], u1i=ai[1]-ai[5];
  const float u2r=ar[3]+ar[7], u2i=ai[3]+ai[7];
  const float u3r=ar[3]-ar[7], u3i=ai[3]-ai[7];
  const float O0r=u0r+u2r, O0i=u0i+u2i;
  const float O1r=u1r+u3i, O1i=u1i-u3r;
  const float O2r=u0r-u2r, O2i=u0i-u2i;
  const float O3r=u1r-u3i, O3i=u1i+u3r;
  const float w1r =  C*(O1r+O1i), w1i = C*(O1i-O1r);
  const float w2r =  O2i,         w2i = -O2r;
  const float w3r =  C*(O3i-O3r), w3i = -C*(O3r+O3i);
  ar[0]=E0r+O0r; ai[0]=E0i+O0i;
  ar[4]=E0r-O0r; ai[4]=E0i-O0i;
  ar[1]=E1r+w1r; ai[1]=E1i+w1i;
  ar[5]=E1r-w1r; ai[5]=E1i-w1i;
  ar[2]=E2r+w2r; ai[2]=E2i+w2i;
  ar[6]=E2r-w2r; ai[6]=E2i-w2i;
  ar[3]=E3r+w3r; ai[3]=E3i+w3i;
  ar[7]=E3r-w3r; ai[7]=E3i-w3i;
}

// stats LDS slots (per wave): 0 SUMSQ, 1 ALT, 2..11 R1..R10, 12 STR, 13 STR2,
// 14 SC, 15 SC2, 16 SUMX, 17..26 Slo, 27..36 Shi pool, 37 x0, 38 xl
__global__ void __launch_bounds__(256, 2)
sr_kernel(const float* __restrict__ x,
          const float* __restrict__ ln_w, const float* __restrict__ ln_b,
          const float* __restrict__ w1, const float* __restrict__ b1,
          const float* __restrict__ w2, const float* __restrict__ b2,
          float* __restrict__ out, int B)
{
  __shared__ __align__(16) float2 buf2[4][512];     // 4KB per wave
  __shared__ __align__(16) float stats2[4][40];

  const int tid = threadIdx.x;
  const int t   = tid & 63;
  const int wv  = tid >> 6;
  const int row = blockIdx.x * 4 + wv;
  if (row >= B) return;
  const float* __restrict__ xr = x + (size_t)row * 1024;
  float2* buf = buf2[wv];
  float*  st  = stats2[wv];

  // ---- loads: own 16 + 12 right + 12 left neighbors ----
  const int c0 = t * 16;
  float vv[28];
  {
    const float4 a0 = *reinterpret_cast<const float4*>(xr + c0);
    const float4 a1 = *reinterpret_cast<const float4*>(xr + c0 + 4);
    const float4 a2 = *reinterpret_cast<const float4*>(xr + c0 + 8);
    const float4 a3 = *reinterpret_cast<const float4*>(xr + c0 + 12);
    vv[0]=a0.x; vv[1]=a0.y; vv[2]=a0.z; vv[3]=a0.w;
    vv[4]=a1.x; vv[5]=a1.y; vv[6]=a1.z; vv[7]=a1.w;
    vv[8]=a2.x; vv[9]=a2.y; vv[10]=a2.z; vv[11]=a2.w;
    vv[12]=a3.x; vv[13]=a3.y; vv[14]=a3.z; vv[15]=a3.w;
    if (t < 63) {
      const float4 n0 = *reinterpret_cast<const float4*>(xr + c0 + 16);
      const float4 n1 = *reinterpret_cast<const float4*>(xr + c0 + 20);
      const float4 n2 = *reinterpret_cast<const float4*>(xr + c0 + 24);
      vv[16]=n0.x; vv[17]=n0.y; vv[18]=n0.z; vv[19]=n0.w;
      vv[20]=n1.x; vv[21]=n1.y; vv[22]=n1.z; vv[23]=n1.w;
      vv[24]=n2.x; vv[25]=n2.y; vv[26]=n2.z; vv[27]=n2.w;
    } else {
#pragma unroll
      for (int j = 16; j < 28; ++j) vv[j] = 0.f;
    }
  }
  float pv[12];
  if (t > 0) {
    const float4 p0 = *reinterpret_cast<const float4*>(xr + c0 - 12);
    const float4 p1 = *reinterpret_cast<const float4*>(xr + c0 - 8);
    const float4 p2 = *reinterpret_cast<const float4*>(xr + c0 - 4);
    pv[0]=p0.x; pv[1]=p0.y; pv[2]=p0.z; pv[3]=p0.w;
    pv[4]=p1.x; pv[5]=p1.y; pv[6]=p1.z; pv[7]=p1.w;
    pv[8]=p2.x; pv[9]=p2.y; pv[10]=p2.z; pv[11]=p2.w;
  } else {
#pragma unroll
    for (int j = 0; j < 12; ++j) pv[j] = 0.f;
  }

  // ---- stash z[8t+j] = x[16t+2j] + i x[16t+2j+1] into LDS now; the long
  // stats/scan/trend VALU block below hides the ds latency; strided read later.
#pragma unroll
  for (int j = 0; j < 8; ++j)
    buf[FLS(8*t + j)] = make_float2(vv[2*j], vv[2*j+1]);

  // ---- per-thread stats (scalar fmaf — no packed-pair register shuffling) ----
  {
    float sumsq = 0.f, alt = 0.f;
#pragma unroll
    for (int j = 0; j < 16; ++j) {
      sumsq = fmaf(vv[j], vv[j], sumsq);
      alt += (j & 1) ? -vv[j] : vv[j];
    }
    float r;
    r = wave_red_add(sumsq); if (t == 63) st[0] = r;
    r = wave_red_add(alt);   if (t == 63) st[1] = r;
  }
#pragma unroll
  for (int k = 1; k <= 10; ++k) {
    float acc = 0.f;
#pragma unroll
    for (int j = 0; j < 16; ++j) acc = fmaf(vv[j], vv[j+k], acc);
    float r = wave_red_add(acc);
    if (t == 63) st[1 + k] = r;
  }

  // ---- prefix sums ----
  float s[16];
  s[0] = vv[0];
#pragma unroll
  for (int j = 1; j < 16; ++j) s[j] = s[j-1] + vv[j];
  const float cs16 = s[15];
  const float incl = wave_iscan_add(cs16);
  const float excl = incl - cs16;
#pragma unroll
  for (int j = 0; j < 16; ++j) s[j] += excl;
  if (t == 63) st[16] = incl;                       // SUMX
  if (t == 0) {
#pragma unroll
    for (int q = 0; q < 10; ++q) st[17 + q] = s[q];
    st[37] = vv[0];
  }
  if (t == 63) {
#pragma unroll
    for (int q = 0; q < 10; ++q) st[27 + q] = s[5 + q];
    st[38] = vv[15];
  }

  // ---- trend via sliding +-12 window ----
  float trv[16];
  float str = 0.f, str2 = 0.f;
  {
    float wsum = 0.f;
#pragma unroll
    for (int j = 0; j < 12; ++j) wsum += pv[j];
#pragma unroll
    for (int j = 0; j <= 12; ++j) wsum += vv[j];
#pragma unroll
    for (int jj = 0; jj < 16; ++jj) {
      if (jj > 0) {
        const float addv = vv[jj + 12];
        const float subv = (jj < 13) ? pv[jj - 1] : vv[jj - 13];
        wsum += addv - subv;
      }
      float swc = wsum;
      if (t == 0  && jj < 12) swc += (float)(12 - jj) * vv[0];
      if (t == 63 && jj >= 4) swc += (float)(jj - 3) * vv[15];
      const float tv = swc * 0.04f;
      trv[jj] = tv;
      str += tv;
      str2 = fmaf(tv, tv, str2);
    }
  }
  const float tincl = wave_iscan_add(str);
  if (t == 63) st[12] = tincl;
  { float r = wave_red_add(str2); if (t == 63) st[13] = r; }
  {
    const float texcl = tincl - str;
    float run = texcl, sc = 0.f, sc2 = 0.f;
#pragma unroll
    for (int jj = 0; jj < 16; ++jj) {
      run += trv[jj];
      const float cv = s[jj] - run;
      sc += cv;
      sc2 = fmaf(cv, cv, sc2);
    }
    float r;
    r = wave_red_add(sc);  if (t == 63) st[14] = r;
    r = wave_red_add(sc2); if (t == 63) st[15] = r;
  }

  // ==================== half-length real FFT: Z = FFT_512(z), z from LDS ====================
  float zr[8], zi[8];
#pragma unroll
  for (int p = 0; p < 8; ++p) {
    const float2 v = buf[FLS(t + 64*p)];
    zr[p] = v.x; zi[p] = v.y;
  }
  dft8(zr, zi);
  {
    const float a1 = -0.012271846303085130f * (float)t;   // -2pi/512 * t
    const float c1 = __cosf(a1), s1 = __sinf(a1);
    const float c2=c1*c1-s1*s1, s2=2.f*c1*s1;
    const float c3=c2*c1-s2*s1, s3=s2*c1+c2*s1;
    const float c4=c2*c2-s2*s2, s4=2.f*c2*s2;
    const float c5=c4*c1-s4*s1, s5=s4*c1+c4*s1;
    const float c6=c3*c3-s3*s3, s6=2.f*c3*s3;
    const float c7=c6*c1-s6*s1, s7=s6*c1+c6*s1;
    const float cq[8] = {1.f,c1,c2,c3,c4,c5,c6,c7};
    const float sq[8] = {0.f,s1,s2,s3,s4,s5,s6,s7};
#pragma unroll
    for (int q = 1; q < 8; ++q) {
      const float r0 = zr[q]*cq[q] - zi[q]*sq[q];
      zi[q] = zr[q]*sq[q] + zi[q]*cq[q];
      zr[q] = r0;
    }
  }
  // transpose 1: w_q stored at q*64 + c
#pragma unroll
  for (int q = 0; q < 8; ++q)
    buf[FLS(q*64 + t)] = make_float2(zr[q], zi[q]);
  const int qq = t >> 3;
  const int dd = t & 7;
  const int qb = qq << 6;
#pragma unroll
  for (int e = 0; e < 8; ++e) {
    const float2 z = buf[FLS(qb + dd + 8*e)];
    zr[e] = z.x; zi[e] = z.y;
  }
  dft8(zr, zi);
  {
    const float a1 = -0.098174770424681039f * (float)dd;  // -2pi/64 * d
    const float c1 = __cosf(a1), s1 = __sinf(a1);
    const float c2=c1*c1-s1*s1, s2=2.f*c1*s1;
    const float c3=c2*c1-s2*s1, s3=s2*c1+c2*s1;
    const float c4=c2*c2-s2*s2, s4=2.f*c2*s2;
    const float c5=c4*c1-s4*s1, s5=s4*c1+c4*s1;
    const float c6=c3*c3-s3*s3, s6=2.f*c3*s3;
    const float c7=c6*c1-s6*s1, s7=s6*c1+c6*s1;
    const float cq[8] = {1.f,c1,c2,c3,c4,c5,c6,c7};
    const float sq[8] = {0.f,s1,s2,s3,s4,s5,s6,s7};
#pragma unroll
    for (int q = 1; q < 8; ++q) {
      const float r0 = zr[q]*cq[q] - zi[q]*sq[q];
      zi[q] = zr[q]*sq[q] + zi[q]*cq[q];
      zr[q] = r0;
    }
  }
  // transpose 2: v_{q,s}[d] stored at q*64 + s*8 + d
#pragma unroll
  for (int sA = 0; sA < 8; ++sA)
    buf[FLS(qb + sA*8 + dd)] = make_float2(zr[sA], zi[sA]);
#pragma unroll
  for (int d = 0; d < 8; ++d) {
    const float2 z = buf[FLS(qb + dd*8 + d)];
    zr[d] = z.x; zi[d] = z.y;
  }
  dft8(zr, zi);
  // register r holds Z[k], k = 64r + 8*dd + qq

  // ---- untangle to rfft psd: write Z, read conjugate partner ----
#pragma unroll
  for (int r = 0; r < 8; ++r)
    buf[FLS(t*8 + r)] = make_float2(zr[r], zi[r]);
  const int pl = (t == 0) ? 0 : ((t < 8) ? (8 - t) : (71 - t));
  const bool lane0 = (t == 0);
  const float kb = (float)((dd << 3) + qq);
  const float ab = -0.0061359231515425649f * kb;          // -pi/512 * (8s+q)
  const float wbr = __cosf(ab), wbi = __sinf(ab);
  constexpr float RCr[8] = {1.f, 0.98078528040323044f, 0.92387953251128674f, 0.83146961230254524f,
                            0.70710678118654752f, 0.55557023301960222f, 0.38268343236508977f, 0.19509032201612827f};
  constexpr float RCi[8] = {0.f, -0.19509032201612827f, -0.38268343236508977f, -0.55557023301960222f,
                            -0.70710678118654752f, -0.83146961230254524f, -0.92387953251128674f, -0.98078528040323044f};
  float psum = 0.f, pmax = 0.f, plog = 0.f;
#pragma unroll
  for (int r = 0; r < 8; ++r) {
    const int rho = lane0 ? ((8 - r) & 7) : (7 - r);
    const float2 zp = buf[FLS(pl*8 + rho)];
    const float Er = 0.5f*(zr[r] + zp.x);
    const float Ei = 0.5f*(zi[r] - zp.y);
    const float Or = 0.5f*(zi[r] + zp.y);
    const float Oi = -0.5f*(zr[r] - zp.x);
    const float wr = wbr*RCr[r] - wbi*RCi[r];
    const float wi = wbr*RCi[r] + wbi*RCr[r];
    const float Xr = Er + wr*Or - wi*Oi;
    const float Xi = Ei + wr*Oi + wi*Or;
    const float pp = fmaxf(Xr*Xr + Xi*Xi, EPSF);
    psum += pp;
    pmax = fmaxf(pmax, pp);
    plog += pp * __logf(pp);
  }
  const float PSUM = rl(wave_red_add(psum), 63);
  const float PMAX = rl(wave_red_max_pos(pmax), 63);
  const float PLOG = rl(wave_red_add(plog), 63);

  // ---- stashed uniform stats ----
  const float SUMSQ = st[0];
  const float ALT   = st[1];
  const float STR   = st[12];
  const float STR2  = st[13];
  const float SC    = st[14];
  const float SC2   = st[15];
  const float SUMX  = st[16];
  const float x0    = st[37];
  const float xl    = st[38];

  // ---- features (bins 0..511 in PSUM/PLOG/PMAX; bin 512 = ALT^2 added here) ----
  const float p512b = fmaxf(ALT * ALT, EPSF);
  const float Sr    = PSUM + p512b;
  const float invS  = 1.f / Sr;
  const float PLr   = PLOG + p512b * __logf(p512b);
  const float ent   = __logf(Sr) - PLr * invS;
  const float PMX   = fmaxf(PMAX, p512b);

  const float m = SUMX * (1.f / 1024.f);
  const float den = SUMSQ - 1024.f * m * m + EPSF;
  const float invden = 1.f / den;
  float acf1 = 0.f, acf2 = 0.f, lbq = 0.f, R1v = 0.f;
#pragma unroll
  for (int k = 1; k <= 10; ++k) {
    const float Rkv = st[1 + k];
    const float Slo = st[16 + k];
    const float Shi = st[37 - k];
    const float num = Rkv - m * (Shi + (SUMX - Slo)) + (float)(1024 - k) * m * m;
    const float a = fminf(fmaxf(num * invden, -1.f), 1.f);
    if (k == 1) { acf1 = a; R1v = Rkv; }
    else if (k == 2) acf2 = a;
    lbq += a * a;
  }
  const float spent = fminf(fmaxf(ent / (__logf(513.f + EPSF) + EPSF), 0.f), 1.f);
  const float peak  = fminf(fmaxf(PMX / (Sr + EPSF), 0.f), 1.f);
  const float phi = fminf(fmaxf(R1v / ((SUMSQ - xl * xl) + EPSF), -1.f), 1.f);
  const float invn = 1.f / 1023.f;
  const float sum_d2 = 2.f * SUMSQ - x0 * x0 - xl * xl - 2.f * R1v;
  const float md = (xl - x0) * invn;
  const float diff_var = sum_d2 * invn - md * md;
  const float tstr = STR2 * (1.f / 1024.f) - (STR * (1.f / 1024.f)) * (STR * (1.f / 1024.f));
  const float varx = SUMSQ * (1.f / 1024.f) - m * m;
  const float mc = SC * (1.f / 1024.f);
  const float kpss = (SC2 * (1.f / 1024.f) - mc * mc) / (varx + 1e-8f);

  float f[9] = {acf1, acf2, spent, phi, diff_var, tstr, kpss, lbq, peak};
  float fm = 0.f;
#pragma unroll
  for (int d = 0; d < 9; ++d) fm += f[d];
  fm *= (1.f / 9.f);
  float fv = 0.f;
#pragma unroll
  for (int d = 0; d < 9; ++d) { const float tt = f[d] - fm; fv = fmaf(tt, tt, fv); }
  fv *= (1.f / 9.f);
  const float inl = 1.f / sqrtf(fv + 1e-5f);
  float fn[9];
#pragma unroll
  for (int d = 0; d < 9; ++d) fn[d] = (f[d] - fm) * inl * ln_w[d] + ln_b[d];

  // ---- MLP: hidden unit = lane ----
  float h = b1[t];
#pragma unroll
  for (int d = 0; d < 9; ++d) h = fmaf(fn[d], w1[d * 64 + t], h);
  h = fmaxf(h, 0.f);
  float l0 = h * w2[t * 3 + 0];
  float l1 = h * w2[t * 3 + 1];
  float l2 = h * w2[t * 3 + 2];
  l0 = wave_red_add(l0);
  l1 = wave_red_add(l1);
  l2 = wave_red_add(l2);
  const float L0 = rl(l0, 63) + b2[0];
  const float L1 = rl(l1, 63) + b2[1];
  const float L2 = rl(l2, 63) + b2[2];
  if (t == 0) {
    const float mx = fmaxf(L0, fmaxf(L1, L2));
    const float e0 = __expf(L0 - mx), e1 = __expf(L1 - mx), e2 = __expf(L2 - mx);
    const float is = 1.f / (e0 + e1 + e2);
    float* o = out + (size_t)row * 3;
    o[0] = e0 * is; o[1] = e1 * is; o[2] = e2 * is;
    float* fo = out + (size_t)B * 3 + (size_t)row * 9;
    fo[0] = fn[0]; fo[1] = fn[1]; fo[2] = fn[2]; fo[3] = fn[3]; fo[4] = fn[4];
    fo[5] = fn[5]; fo[6] = fn[6]; fo[7] = fn[7]; fo[8] = fn[8];
  }
}

extern "C" void kernel_launch(void* const* d_in, const int* in_sizes, int n_in,
                              void* d_out, int out_size, void* d_ws, size_t ws_size,
                              hipStream_t stream) {
  (void)n_in; (void)out_size; (void)d_ws; (void)ws_size;
  const float* x    = (const float*)d_in[0];
  const float* ln_w = (const float*)d_in[1];
  const float* ln_b = (const float*)d_in[2];
  const float* w1   = (const float*)d_in[3];
  const float* b1   = (const float*)d_in[4];
  const float* w2   = (const float*)d_in[5];
  const float* b2   = (const float*)d_in[6];
  float* out = (float*)d_out;
  const int B = in_sizes[0] / 1024;
  sr_kernel<<<(B + 3) / 4, 256, 0, stream>>>(x, ln_w, ln_b, w1, b1, w2, b2, out, B);
}